// Round 3
// baseline (879.042 us; speedup 1.0000x reference)
//
#include <hip/hip_runtime.h>
#include <math.h>

#define NPTS 16384
#define KN 32
#define C 256
#define NQ 8192              // 8 * 1024 queries
#define PF_ELEMS (NQ * C)

#define W1P_ELEMS (3 * 16 * 64 * 8)                 // 24576  (Ktiles=3, Ntiles=16)
#define W2P_ELEMS (8 * 16 * 64 * 8)                 // 65536  (Ktiles=8)

typedef _Float16 half8 __attribute__((ext_vector_type(8)));
typedef _Float16 half4v __attribute__((ext_vector_type(4)));
typedef float f32x4 __attribute__((ext_vector_type(4)));

// ---------------------------------------------------------------------------
// Pack W1 (91x256, K-padded to 96) and W2 (256x256) into f16 B-fragment order
// for mfma_f32_16x16x32_f16 (layout verified in round 2):
//   flat = ((ktile*16 + ntile)*64 + lane)*8 + j
//   k = ktile*32 + (lane>>4)*8 + j ;  n = ntile*16 + (lane&15)
// ---------------------------------------------------------------------------
__global__ void prep_w_kernel(const float* __restrict__ W1,
                              const float* __restrict__ W2,
                              _Float16* __restrict__ wp) {
    const int e = blockIdx.x * 256 + threadIdx.x;
    if (e < W1P_ELEMS) {
        const int j = e & 7, lane = (e >> 3) & 63, nt = (e >> 9) & 15, kt = e >> 13;
        const int k = kt * 32 + (lane >> 4) * 8 + j;
        const int n = nt * 16 + (lane & 15);
        wp[e] = (_Float16)((k < 91) ? W1[k * C + n] : 0.0f);
    } else {
        const int e2 = e - W1P_ELEMS;
        const int j = e2 & 7, lane = (e2 >> 3) & 63, nt = (e2 >> 9) & 15, kt = e2 >> 13;
        const int k = kt * 32 + (lane >> 4) * 8 + j;
        const int n = nt * 16 + (lane & 15);
        wp[e] = (_Float16)W2[k * C + n];
    }
}

// tanh-approx GeLU: 0.5x(1+tanh(0.79788456(x+0.044715x^3))), max err ~3e-4.
// 1+tanh(u) = 2 - 2/(e^{2u}+1)  =>  y = x * (1 - 1/(e^{2u}+1))
__device__ __forceinline__ float gelu_tanh(float x) {
    const float t  = x * x;
    const float p2 = fmaf(t, 0.0713548162726f, 1.59576912161f); // 2*0.79788456*(0.044715, 1)
    const float e  = __expf(x * p2);
    return x - x * __builtin_amdgcn_rcpf(e + 1.0f);
}

// ---------------------------------------------------------------------------
// Fused: ball-query + gather/posenc + MLP1(LN,GeLU) + MLP2(LN) + max.
// One query per 256-thread block (4 waves). f16 MFMA GEMMs, fp32 LN stats.
// LDS ~40 KB -> 4 blocks/CU.
// ---------------------------------------------------------------------------
__global__ void __launch_bounds__(256, 4)
encoder_fused(const float* __restrict__ xyz,
              const float* __restrict__ pf,
              const float* __restrict__ ctr,
              const float* __restrict__ b1, const float* __restrict__ g1,
              const float* __restrict__ be1,
              const float* __restrict__ b2, const float* __restrict__ g2,
              const float* __restrict__ be2,
              const _Float16* __restrict__ w1p,
              const _Float16* __restrict__ w2p,
              float* __restrict__ out0,      // patch_feature [8192][256]
              float* __restrict__ out1) {    // neighbor idx as float [8192][32]
    const int q = blockIdx.x;
    const int b = q >> 10;
    const int t = threadIdx.x;
    const int w = t >> 6;
    const int lane = t & 63;
    const int quad = lane >> 4;
    const int l15  = lane & 15;

    // H16: layer outputs, f16, row stride 264 (132 words; uniform bank spread)
    __shared__ __align__(16) unsigned char H16raw[KN * 264 * 2];   // 16896
    // R2: union { Xs f16[32][104] (GEMM1 input) ; R2h f16[32][264] (GEMM2 out) }
    __shared__ __align__(16) unsigned char R2raw[KN * 264 * 2];    // 16896
    __shared__ float lnp[6 * 256];                                  // b1,g1,be1,b2,g2,be2
    __shared__ int nbr[KN];
    __shared__ int wcnt[4];

    _Float16 (*H16)[264] = (_Float16(*)[264])H16raw;
    _Float16 (*Xs)[104]  = (_Float16(*)[104])R2raw;
    _Float16 (*R2h)[264] = (_Float16(*)[264])R2raw;
    float* lnb1  = lnp;        float* lng1 = lnp + 256;  float* lnbe1 = lnp + 512;
    float* lnb2  = lnp + 768;  float* lng2 = lnp + 1024; float* lnbe2 = lnp + 1280;

    // stage LN params (visible after the ball-loop / phase-1 barriers)
    lnp[t]        = b1[t];  lnp[256 + t]  = g1[t]; lnp[512 + t]  = be1[t];
    lnp[768 + t]  = b2[t];  lnp[1024 + t] = g2[t]; lnp[1280 + t] = be2[t];

    // ---- Phase 0: ball query, block-wide ordered compaction ----
    // Reference's sort+slice == first 32 indices (ascending) within radius.
    // Distance formula replicated exactly (fp32, unfused) as rounds 1-2.
    const float* xb = xyz + (size_t)b * NPTS * 3;
    const float cx = ctr[q * 3 + 0];
    const float cy = ctr[q * 3 + 1];
    const float cz = ctr[q * 3 + 2];
    const float sc = __fadd_rn(__fadd_rn(__fmul_rn(cx, cx), __fmul_rn(cy, cy)),
                               __fmul_rn(cz, cz));

    int found = 0;
    for (int base = 0; base < NPTS; base += 256) {
        const int n = base + t;
        const float px = xb[n * 3 + 0];
        const float py = xb[n * 3 + 1];
        const float pz = xb[n * 3 + 2];
        const float sp = __fadd_rn(__fadd_rn(__fmul_rn(px, px), __fmul_rn(py, py)),
                                   __fmul_rn(pz, pz));
        const float dt = __fadd_rn(__fadd_rn(__fmul_rn(cx, px), __fmul_rn(cy, py)),
                                   __fmul_rn(cz, pz));
        const float sqr = __fsub_rn(__fadd_rn(sc, sp), __fmul_rn(2.0f, dt));
        const bool inball = (sqr <= 0.0625f);

        const unsigned long long m = __ballot(inball);
        if (lane == 0) wcnt[w] = (int)__popcll(m);
        __syncthreads();
        int pre = found;
        if (w > 0) pre += wcnt[0];
        if (w > 1) pre += wcnt[1];
        if (w > 2) pre += wcnt[2];
        const int tot = found + wcnt[0] + wcnt[1] + wcnt[2] + wcnt[3];
        const int pos = pre + (int)__popcll(m & ((1ull << lane) - 1ull));
        if (inball && pos < KN) nbr[pos] = n;
        found = tot;
        __syncthreads();
        if (found >= KN) break;       // 'found' is block-uniform
    }
    const int count = (found < KN) ? found : KN;
    const int first = (count > 0) ? nbr[0] : NPTS;

    if (t < KN)
        out1[(size_t)q * KN + t] = (float)((t < count) ? nbr[t] : first);

    // ---- Phase 1: gather + rel + posenc into Xs (f16, K-padded to 96) ----
    {
        const int k  = t >> 3;          // neighbor row 0..31
        const int tc = t & 7;           // 8 threads per row
        const int nidx = (k < count) ? nbr[k] : first;
        const int n = (nidx < NPTS) ? nidx : NPTS - 1;   // JAX OOB gather clamp
        const float rx = xb[n * 3 + 0] - cx;
        const float ry = xb[n * 3 + 1] - cy;
        const float rz = xb[n * 3 + 2] - cz;
        const float* pfr = pf + ((size_t)b * NPTS + n) * 64;

        const float4 f0 = *(const float4*)(pfr + tc * 8);
        const float4 f1 = *(const float4*)(pfr + tc * 8 + 4);
        half8 hv;
        hv[0] = (_Float16)f0.x; hv[1] = (_Float16)f0.y;
        hv[2] = (_Float16)f0.z; hv[3] = (_Float16)f0.w;
        hv[4] = (_Float16)f1.x; hv[5] = (_Float16)f1.y;
        hv[6] = (_Float16)f1.z; hv[7] = (_Float16)f1.w;
        *(half8*)&Xs[k][tc * 8] = hv;

        half4v ov;
        #pragma unroll
        for (int j = 0; j < 4; ++j) {
            const int c = 64 + tc * 4 + j;
            float v;
            if (c < 67) {
                v = (c == 64) ? rx : ((c == 65) ? ry : rz);
            } else if (c < 91) {
                const int jj = c - 67;
                const int d = jj >> 3;
                const int mm = jj & 7;
                const float f = (float)(1 << (mm & 3));
                const float r = (d == 0) ? rx : ((d == 1) ? ry : rz);
                v = (mm < 4) ? __sinf(r * f) : __cosf(r * f);
            } else {
                v = 0.0f;
            }
            ov[j] = (_Float16)v;
        }
        *(half4v*)&Xs[k][64 + tc * 4] = ov;
    }
    __syncthreads();

    // ---- Phase 2: GEMM1  X[32x96] @ W1[96x256] -> H16 (+b1, f16) ----
    {
        f32x4 acc[2][4];
        #pragma unroll
        for (int mt = 0; mt < 2; ++mt)
            #pragma unroll
            for (int nt = 0; nt < 4; ++nt)
                acc[mt][nt] = (f32x4){0.f, 0.f, 0.f, 0.f};

        #pragma unroll
        for (int kt = 0; kt < 3; ++kt) {
            const half8 a0 = *(const half8*)&Xs[l15][kt * 32 + quad * 8];
            const half8 a1 = *(const half8*)&Xs[16 + l15][kt * 32 + quad * 8];
            #pragma unroll
            for (int nt = 0; nt < 4; ++nt) {
                const int ntg = w * 4 + nt;
                const half8 bf = *(const half8*)&w1p[((kt * 16 + ntg) * 64 + lane) * 8];
                acc[0][nt] = __builtin_amdgcn_mfma_f32_16x16x32_f16(a0, bf, acc[0][nt], 0, 0, 0);
                acc[1][nt] = __builtin_amdgcn_mfma_f32_16x16x32_f16(a1, bf, acc[1][nt], 0, 0, 0);
            }
        }
        #pragma unroll
        for (int nt = 0; nt < 4; ++nt) {
            const int col = w * 64 + nt * 16 + l15;
            const float bb = lnb1[col];
            #pragma unroll
            for (int mt = 0; mt < 2; ++mt)
                #pragma unroll
                for (int r = 0; r < 4; ++r)
                    H16[mt * 16 + quad * 4 + r][col] = (_Float16)(acc[mt][nt][r] + bb);
        }
    }
    __syncthreads();

    const int row = t >> 3;         // LN row ownership: thread = (row, octet p)
    const int p   = t & 7;          // owns cols p*32 .. p*32+31

    // ---- Phase 3: LN1 + GeLU, in place on H16 ----
    {
        _Float16* hrow = &H16[row][p * 32];
        float f[32];
        float s = 0.0f, s2 = 0.0f;
        #pragma unroll
        for (int jo = 0; jo < 4; ++jo) {
            const int j = (jo + p) & 3;                 // bank-staggered
            const half8 hv = *(const half8*)(hrow + j * 8);
            #pragma unroll
            for (int e = 0; e < 8; ++e) {
                const float x = (float)hv[e];
                f[j * 8 + e] = x;
                s += x;
                s2 = fmaf(x, x, s2);
            }
        }
        #pragma unroll
        for (int off = 1; off < 8; off <<= 1) {
            s  += __shfl_xor(s, off, 64);
            s2 += __shfl_xor(s2, off, 64);
        }
        const float mu  = s * (1.0f / 256.0f);
        const float var = fmaf(s2, 1.0f / 256.0f, -mu * mu);
        const float rs  = __builtin_amdgcn_rsqf(var + 1e-5f);

        #pragma unroll
        for (int jo = 0; jo < 4; ++jo) {
            const int j = (jo + p) & 3;
            const float* gp = &lng1[p * 32 + j * 8];
            const float* bp = &lnbe1[p * 32 + j * 8];
            half8 hv;
            #pragma unroll
            for (int e = 0; e < 8; ++e) {
                const float y = fmaf((f[j * 8 + e] - mu) * rs, gp[e], bp[e]);
                hv[e] = (_Float16)gelu_tanh(y);
            }
            *(half8*)(hrow + j * 8) = hv;
        }
    }
    __syncthreads();

    // ---- Phase 4: GEMM2  H[32x256] @ W2[256x256] -> R2h (+b2, f16) ----
    // R2 region (Xs) is dead since the phase-2-end barrier; safe to overwrite.
    {
        f32x4 acc[2][4];
        #pragma unroll
        for (int mt = 0; mt < 2; ++mt)
            #pragma unroll
            for (int nt = 0; nt < 4; ++nt)
                acc[mt][nt] = (f32x4){0.f, 0.f, 0.f, 0.f};

        #pragma unroll
        for (int kt = 0; kt < 8; ++kt) {
            const half8 a0 = *(const half8*)&H16[l15][kt * 32 + quad * 8];
            const half8 a1 = *(const half8*)&H16[16 + l15][kt * 32 + quad * 8];
            #pragma unroll
            for (int nt = 0; nt < 4; ++nt) {
                const int ntg = w * 4 + nt;
                const half8 bf = *(const half8*)&w2p[((kt * 16 + ntg) * 64 + lane) * 8];
                acc[0][nt] = __builtin_amdgcn_mfma_f32_16x16x32_f16(a0, bf, acc[0][nt], 0, 0, 0);
                acc[1][nt] = __builtin_amdgcn_mfma_f32_16x16x32_f16(a1, bf, acc[1][nt], 0, 0, 0);
            }
        }
        #pragma unroll
        for (int nt = 0; nt < 4; ++nt) {
            const int col = w * 64 + nt * 16 + l15;
            const float bb = lnb2[col];
            #pragma unroll
            for (int mt = 0; mt < 2; ++mt)
                #pragma unroll
                for (int r = 0; r < 4; ++r)
                    R2h[mt * 16 + quad * 4 + r][col] = (_Float16)(acc[mt][nt][r] + bb);
        }
    }
    __syncthreads();

    // ---- Phase 5: LN2 (no activation), in place on R2h ----
    {
        _Float16* hrow = &R2h[row][p * 32];
        float f[32];
        float s = 0.0f, s2 = 0.0f;
        #pragma unroll
        for (int jo = 0; jo < 4; ++jo) {
            const int j = (jo + p) & 3;
            const half8 hv = *(const half8*)(hrow + j * 8);
            #pragma unroll
            for (int e = 0; e < 8; ++e) {
                const float x = (float)hv[e];
                f[j * 8 + e] = x;
                s += x;
                s2 = fmaf(x, x, s2);
            }
        }
        #pragma unroll
        for (int off = 1; off < 8; off <<= 1) {
            s  += __shfl_xor(s, off, 64);
            s2 += __shfl_xor(s2, off, 64);
        }
        const float mu  = s * (1.0f / 256.0f);
        const float var = fmaf(s2, 1.0f / 256.0f, -mu * mu);
        const float rs  = __builtin_amdgcn_rsqf(var + 1e-5f);

        #pragma unroll
        for (int jo = 0; jo < 4; ++jo) {
            const int j = (jo + p) & 3;
            const float* gp = &lng2[p * 32 + j * 8];
            const float* bp = &lnbe2[p * 32 + j * 8];
            half8 hv;
            #pragma unroll
            for (int e = 0; e < 8; ++e) {
                const float y = fmaf((f[j * 8 + e] - mu) * rs, gp[e], bp[e]);
                hv[e] = (_Float16)y;
            }
            *(half8*)(hrow + j * 8) = hv;
        }
    }
    __syncthreads();

    // ---- Phase 6: max over K per channel, write out ----
    {
        float m = -INFINITY;
        #pragma unroll
        for (int k = 0; k < KN; ++k)
            m = fmaxf(m, (float)R2h[k][t]);
        out0[(size_t)q * C + t] = m;
    }
}

extern "C" void kernel_launch(void* const* d_in, const int* in_sizes, int n_in,
                              void* d_out, int out_size, void* d_ws, size_t ws_size,
                              hipStream_t stream) {
    const float* xyz = (const float*)d_in[0];
    const float* pf  = (const float*)d_in[1];
    const float* ctr = (const float*)d_in[2];
    const float* W1  = (const float*)d_in[3];
    const float* b1  = (const float*)d_in[4];
    const float* g1  = (const float*)d_in[5];
    const float* be1 = (const float*)d_in[6];
    const float* W2  = (const float*)d_in[7];
    const float* b2  = (const float*)d_in[8];
    const float* g2  = (const float*)d_in[9];
    const float* be2 = (const float*)d_in[10];

    float* out = (float*)d_out;
    _Float16* wp = (_Float16*)d_ws;

    prep_w_kernel<<<(W1P_ELEMS + W2P_ELEMS) / 256, 256, 0, stream>>>(W1, W2, wp);
    encoder_fused<<<NQ, 256, 0, stream>>>(xyz, pf, ctr,
                                          b1, g1, be1, b2, g2, be2,
                                          wp, wp + W1P_ELEMS,
                                          out, out + PF_ELEMS);
}

// Round 4
// 210.048 us; speedup vs baseline: 4.1850x; 4.1850x over previous
//
#include <hip/hip_runtime.h>
#include <math.h>

#define NPTS 16384
#define KN 32
#define C 256
#define NQ 8192              // 8 * 1024 queries
#define PF_ELEMS (NQ * C)

#define W1P_ELEMS (3 * 16 * 64 * 8)                 // 24576  (Ktiles=3, Ntiles=16)
#define W2P_ELEMS (8 * 16 * 64 * 8)                 // 65536  (Ktiles=8)

typedef _Float16 half8 __attribute__((ext_vector_type(8)));
typedef _Float16 half4v __attribute__((ext_vector_type(4)));
typedef float f32x4 __attribute__((ext_vector_type(4)));

// ---------------------------------------------------------------------------
// Pack W1 (91x256, K-padded to 96) and W2 (256x256) into f16 B-fragment order
// for mfma_f32_16x16x32_f16 (layout verified in round 2):
//   flat = ((ktile*16 + ntile)*64 + lane)*8 + j
//   k = ktile*32 + (lane>>4)*8 + j ;  n = ntile*16 + (lane&15)
// ---------------------------------------------------------------------------
__global__ void prep_w_kernel(const float* __restrict__ W1,
                              const float* __restrict__ W2,
                              _Float16* __restrict__ wp) {
    const int e = blockIdx.x * 256 + threadIdx.x;
    if (e < W1P_ELEMS) {
        const int j = e & 7, lane = (e >> 3) & 63, nt = (e >> 9) & 15, kt = e >> 13;
        const int k = kt * 32 + (lane >> 4) * 8 + j;
        const int n = nt * 16 + (lane & 15);
        wp[e] = (_Float16)((k < 91) ? W1[k * C + n] : 0.0f);
    } else {
        const int e2 = e - W1P_ELEMS;
        const int j = e2 & 7, lane = (e2 >> 3) & 63, nt = (e2 >> 9) & 15, kt = e2 >> 13;
        const int k = kt * 32 + (lane >> 4) * 8 + j;
        const int n = nt * 16 + (lane & 15);
        wp[e] = (_Float16)W2[k * C + n];
    }
}

// tanh-approx GeLU: 0.5x(1+tanh(0.79788456(x+0.044715x^3))), max err ~3e-4.
// 1+tanh(u) = 2 - 2/(e^{2u}+1)  =>  y = x - x/(e^{2u}+1)
__device__ __forceinline__ float gelu_tanh(float x) {
    const float t  = x * x;
    const float p2 = fmaf(t, 0.0713548162726f, 1.59576912161f); // 2*0.79788456*(0.044715, 1)
    const float e  = __expf(x * p2);
    return x - x * __builtin_amdgcn_rcpf(e + 1.0f);
}

// ---------------------------------------------------------------------------
// Fused: ball-query + gather/posenc + MLP1(LN,GeLU) + MLP2(LN) + max.
// One query per 256-thread block (4 waves). f16 MFMA GEMMs, fp32 LN stats.
// LDS ~40 KB -> 4 blocks/CU.
// NOTE (round-3 lesson): NO private arrays with runtime indices — they spill
// to scratch (0.5 GB of HBM traffic, 4x slowdown). All unrolls constant-idx.
// ---------------------------------------------------------------------------
__global__ void __launch_bounds__(256, 4)
encoder_fused(const float* __restrict__ xyz,
              const float* __restrict__ pf,
              const float* __restrict__ ctr,
              const float* __restrict__ b1, const float* __restrict__ g1,
              const float* __restrict__ be1,
              const float* __restrict__ b2, const float* __restrict__ g2,
              const float* __restrict__ be2,
              const _Float16* __restrict__ w1p,
              const _Float16* __restrict__ w2p,
              float* __restrict__ out0,      // patch_feature [8192][256]
              float* __restrict__ out1) {    // neighbor idx as float [8192][32]
    const int q = blockIdx.x;
    const int b = q >> 10;
    const int t = threadIdx.x;
    const int w = t >> 6;
    const int lane = t & 63;
    const int quad = lane >> 4;
    const int l15  = lane & 15;

    // H16: layer-1 output, f16, row stride 264 halves (528 B, 16B-aligned rows)
    __shared__ __align__(16) unsigned char H16raw[KN * 264 * 2];   // 16896
    // R2: union { Xs f16[32][104] (GEMM1 input) ; R2h f16[32][264] (GEMM2 out) }
    __shared__ __align__(16) unsigned char R2raw[KN * 264 * 2];    // 16896
    __shared__ float lnp[6 * 256];                                  // b1,g1,be1,b2,g2,be2
    __shared__ int nbr[KN];
    __shared__ int wcnt[4];

    _Float16 (*H16)[264] = (_Float16(*)[264])H16raw;
    _Float16 (*Xs)[104]  = (_Float16(*)[104])R2raw;
    _Float16 (*R2h)[264] = (_Float16(*)[264])R2raw;
    float* lnb1  = lnp;        float* lng1 = lnp + 256;  float* lnbe1 = lnp + 512;
    float* lnb2  = lnp + 768;  float* lng2 = lnp + 1024; float* lnbe2 = lnp + 1280;

    // stage LN params (visible after the ball-loop / phase-1 barriers)
    lnp[t]        = b1[t];  lnp[256 + t]  = g1[t]; lnp[512 + t]  = be1[t];
    lnp[768 + t]  = b2[t];  lnp[1024 + t] = g2[t]; lnp[1280 + t] = be2[t];

    // ---- Phase 0: ball query, block-wide ordered compaction ----
    // Reference's sort+slice == first 32 indices (ascending) within radius.
    // Distance formula replicated exactly (fp32, unfused) as rounds 1-3.
    const float* xb = xyz + (size_t)b * NPTS * 3;
    const float cx = ctr[q * 3 + 0];
    const float cy = ctr[q * 3 + 1];
    const float cz = ctr[q * 3 + 2];
    const float sc = __fadd_rn(__fadd_rn(__fmul_rn(cx, cx), __fmul_rn(cy, cy)),
                               __fmul_rn(cz, cz));

    int found = 0;
    for (int base = 0; base < NPTS; base += 256) {
        const int n = base + t;
        const float px = xb[n * 3 + 0];
        const float py = xb[n * 3 + 1];
        const float pz = xb[n * 3 + 2];
        const float sp = __fadd_rn(__fadd_rn(__fmul_rn(px, px), __fmul_rn(py, py)),
                                   __fmul_rn(pz, pz));
        const float dt = __fadd_rn(__fadd_rn(__fmul_rn(cx, px), __fmul_rn(cy, py)),
                                   __fmul_rn(cz, pz));
        const float sqr = __fsub_rn(__fadd_rn(sc, sp), __fmul_rn(2.0f, dt));
        const bool inball = (sqr <= 0.0625f);

        const unsigned long long m = __ballot(inball);
        if (lane == 0) wcnt[w] = (int)__popcll(m);
        __syncthreads();
        int pre = found;
        if (w > 0) pre += wcnt[0];
        if (w > 1) pre += wcnt[1];
        if (w > 2) pre += wcnt[2];
        const int tot = found + wcnt[0] + wcnt[1] + wcnt[2] + wcnt[3];
        const int pos = pre + (int)__popcll(m & ((1ull << lane) - 1ull));
        if (inball && pos < KN) nbr[pos] = n;
        found = tot;
        __syncthreads();
        if (found >= KN) break;       // 'found' is block-uniform
    }
    const int count = (found < KN) ? found : KN;
    const int first = (count > 0) ? nbr[0] : NPTS;

    if (t < KN)
        out1[(size_t)q * KN + t] = (float)((t < count) ? nbr[t] : first);

    // ---- Phase 1: gather + rel + posenc into Xs (f16, K-padded to 96) ----
    {
        const int k  = t >> 3;          // neighbor row 0..31
        const int tc = t & 7;           // 8 threads per row
        const int nidx = (k < count) ? nbr[k] : first;
        const int n = (nidx < NPTS) ? nidx : NPTS - 1;   // JAX OOB gather clamp
        const float rx = xb[n * 3 + 0] - cx;
        const float ry = xb[n * 3 + 1] - cy;
        const float rz = xb[n * 3 + 2] - cz;
        const float* pfr = pf + ((size_t)b * NPTS + n) * 64;

        const float4 f0 = *(const float4*)(pfr + tc * 8);
        const float4 f1 = *(const float4*)(pfr + tc * 8 + 4);
        half8 hv;
        hv[0] = (_Float16)f0.x; hv[1] = (_Float16)f0.y;
        hv[2] = (_Float16)f0.z; hv[3] = (_Float16)f0.w;
        hv[4] = (_Float16)f1.x; hv[5] = (_Float16)f1.y;
        hv[6] = (_Float16)f1.z; hv[7] = (_Float16)f1.w;
        *(half8*)&Xs[k][tc * 8] = hv;

        half4v ov;
        #pragma unroll
        for (int j = 0; j < 4; ++j) {
            const int c = 64 + tc * 4 + j;
            float v;
            if (c < 67) {
                v = (c == 64) ? rx : ((c == 65) ? ry : rz);
            } else if (c < 91) {
                const int jj = c - 67;
                const int d = jj >> 3;
                const int mm = jj & 7;
                const float f = (float)(1 << (mm & 3));
                const float r = (d == 0) ? rx : ((d == 1) ? ry : rz);
                v = (mm < 4) ? __sinf(r * f) : __cosf(r * f);
            } else {
                v = 0.0f;
            }
            ov[j] = (_Float16)v;
        }
        *(half4v*)&Xs[k][64 + tc * 4] = ov;
    }
    __syncthreads();

    // ---- Phase 2: GEMM1  X[32x96] @ W1[96x256] -> H16 (+b1, f16) ----
    {
        f32x4 acc[2][4];
        #pragma unroll
        for (int mt = 0; mt < 2; ++mt)
            #pragma unroll
            for (int nt = 0; nt < 4; ++nt)
                acc[mt][nt] = (f32x4){0.f, 0.f, 0.f, 0.f};

        #pragma unroll
        for (int kt = 0; kt < 3; ++kt) {
            const half8 a0 = *(const half8*)&Xs[l15][kt * 32 + quad * 8];
            const half8 a1 = *(const half8*)&Xs[16 + l15][kt * 32 + quad * 8];
            #pragma unroll
            for (int nt = 0; nt < 4; ++nt) {
                const int ntg = w * 4 + nt;
                const half8 bf = *(const half8*)&w1p[((kt * 16 + ntg) * 64 + lane) * 8];
                acc[0][nt] = __builtin_amdgcn_mfma_f32_16x16x32_f16(a0, bf, acc[0][nt], 0, 0, 0);
                acc[1][nt] = __builtin_amdgcn_mfma_f32_16x16x32_f16(a1, bf, acc[1][nt], 0, 0, 0);
            }
        }
        #pragma unroll
        for (int nt = 0; nt < 4; ++nt) {
            const int col = w * 64 + nt * 16 + l15;
            const float bb = lnb1[col];
            #pragma unroll
            for (int mt = 0; mt < 2; ++mt)
                #pragma unroll
                for (int r = 0; r < 4; ++r)
                    H16[mt * 16 + quad * 4 + r][col] = (_Float16)(acc[mt][nt][r] + bb);
        }
    }
    __syncthreads();

    const int row = t >> 3;         // LN row ownership: thread = (row, octet p)
    const int p   = t & 7;          // owns cols p*32 .. p*32+31

    // ---- Phase 3: LN1 + GeLU, in place on H16 (all indices compile-time) ----
    {
        _Float16* hrow = &H16[row][p * 32];
        half8 hv[4];
        float s = 0.0f, s2 = 0.0f;
        #pragma unroll
        for (int j = 0; j < 4; ++j) {
            hv[j] = *(const half8*)(hrow + j * 8);
            #pragma unroll
            for (int e = 0; e < 8; ++e) {
                const float x = (float)hv[j][e];
                s += x;
                s2 = fmaf(x, x, s2);
            }
        }
        #pragma unroll
        for (int off = 1; off < 8; off <<= 1) {
            s  += __shfl_xor(s, off, 64);
            s2 += __shfl_xor(s2, off, 64);
        }
        const float mu  = s * (1.0f / 256.0f);
        const float var = fmaf(s2, 1.0f / 256.0f, -mu * mu);
        const float rs  = __builtin_amdgcn_rsqf(var + 1e-5f);

        #pragma unroll
        for (int j = 0; j < 4; ++j) {
            const f32x4 gA = *(const f32x4*)&lng1[p * 32 + j * 8];
            const f32x4 gB = *(const f32x4*)&lng1[p * 32 + j * 8 + 4];
            const f32x4 bA = *(const f32x4*)&lnbe1[p * 32 + j * 8];
            const f32x4 bB = *(const f32x4*)&lnbe1[p * 32 + j * 8 + 4];
            half8 o;
            #pragma unroll
            for (int e = 0; e < 4; ++e) {
                const float yA = fmaf(((float)hv[j][e]     - mu) * rs, gA[e], bA[e]);
                const float yB = fmaf(((float)hv[j][e + 4] - mu) * rs, gB[e], bB[e]);
                o[e]     = (_Float16)gelu_tanh(yA);
                o[e + 4] = (_Float16)gelu_tanh(yB);
            }
            *(half8*)(hrow + j * 8) = o;
        }
    }
    __syncthreads();

    // ---- Phase 4: GEMM2  H[32x256] @ W2[256x256] -> R2h (+b2, f16) ----
    // R2 region (Xs) is dead since the phase-2-end barrier; safe to overwrite.
    {
        f32x4 acc[2][4];
        #pragma unroll
        for (int mt = 0; mt < 2; ++mt)
            #pragma unroll
            for (int nt = 0; nt < 4; ++nt)
                acc[mt][nt] = (f32x4){0.f, 0.f, 0.f, 0.f};

        #pragma unroll
        for (int kt = 0; kt < 8; ++kt) {
            const half8 a0 = *(const half8*)&H16[l15][kt * 32 + quad * 8];
            const half8 a1 = *(const half8*)&H16[16 + l15][kt * 32 + quad * 8];
            #pragma unroll
            for (int nt = 0; nt < 4; ++nt) {
                const int ntg = w * 4 + nt;
                const half8 bf = *(const half8*)&w2p[((kt * 16 + ntg) * 64 + lane) * 8];
                acc[0][nt] = __builtin_amdgcn_mfma_f32_16x16x32_f16(a0, bf, acc[0][nt], 0, 0, 0);
                acc[1][nt] = __builtin_amdgcn_mfma_f32_16x16x32_f16(a1, bf, acc[1][nt], 0, 0, 0);
            }
        }
        #pragma unroll
        for (int nt = 0; nt < 4; ++nt) {
            const int col = w * 64 + nt * 16 + l15;
            const float bb = lnb2[col];
            #pragma unroll
            for (int mt = 0; mt < 2; ++mt)
                #pragma unroll
                for (int r = 0; r < 4; ++r)
                    R2h[mt * 16 + quad * 4 + r][col] = (_Float16)(acc[mt][nt][r] + bb);
        }
    }
    __syncthreads();

    // ---- Phase 5: LN2 (no activation), in place on R2h ----
    {
        _Float16* hrow = &R2h[row][p * 32];
        half8 hv[4];
        float s = 0.0f, s2 = 0.0f;
        #pragma unroll
        for (int j = 0; j < 4; ++j) {
            hv[j] = *(const half8*)(hrow + j * 8);
            #pragma unroll
            for (int e = 0; e < 8; ++e) {
                const float x = (float)hv[j][e];
                s += x;
                s2 = fmaf(x, x, s2);
            }
        }
        #pragma unroll
        for (int off = 1; off < 8; off <<= 1) {
            s  += __shfl_xor(s, off, 64);
            s2 += __shfl_xor(s2, off, 64);
        }
        const float mu  = s * (1.0f / 256.0f);
        const float var = fmaf(s2, 1.0f / 256.0f, -mu * mu);
        const float rs  = __builtin_amdgcn_rsqf(var + 1e-5f);

        #pragma unroll
        for (int j = 0; j < 4; ++j) {
            const f32x4 gA = *(const f32x4*)&lng2[p * 32 + j * 8];
            const f32x4 gB = *(const f32x4*)&lng2[p * 32 + j * 8 + 4];
            const f32x4 bA = *(const f32x4*)&lnbe2[p * 32 + j * 8];
            const f32x4 bB = *(const f32x4*)&lnbe2[p * 32 + j * 8 + 4];
            half8 o;
            #pragma unroll
            for (int e = 0; e < 4; ++e) {
                o[e]     = (_Float16)fmaf(((float)hv[j][e]     - mu) * rs, gA[e], bA[e]);
                o[e + 4] = (_Float16)fmaf(((float)hv[j][e + 4] - mu) * rs, gB[e], bB[e]);
            }
            *(half8*)(hrow + j * 8) = o;
        }
    }
    __syncthreads();

    // ---- Phase 6: max over K per channel, write out ----
    {
        float m = -INFINITY;
        #pragma unroll
        for (int k = 0; k < KN; ++k)
            m = fmaxf(m, (float)R2h[k][t]);
        out0[(size_t)q * C + t] = m;
    }
}

extern "C" void kernel_launch(void* const* d_in, const int* in_sizes, int n_in,
                              void* d_out, int out_size, void* d_ws, size_t ws_size,
                              hipStream_t stream) {
    const float* xyz = (const float*)d_in[0];
    const float* pf  = (const float*)d_in[1];
    const float* ctr = (const float*)d_in[2];
    const float* W1  = (const float*)d_in[3];
    const float* b1  = (const float*)d_in[4];
    const float* g1  = (const float*)d_in[5];
    const float* be1 = (const float*)d_in[6];
    const float* W2  = (const float*)d_in[7];
    const float* b2  = (const float*)d_in[8];
    const float* g2  = (const float*)d_in[9];
    const float* be2 = (const float*)d_in[10];

    float* out = (float*)d_out;
    _Float16* wp = (_Float16*)d_ws;

    prep_w_kernel<<<(W1P_ELEMS + W2P_ELEMS) / 256, 256, 0, stream>>>(W1, W2, wp);
    encoder_fused<<<NQ, 256, 0, stream>>>(xyz, pf, ctr,
                                          b1, g1, be1, b2, g2, be2,
                                          wp, wp + W1P_ELEMS,
                                          out, out + PF_ELEMS);
}

// Round 5
// 195.385 us; speedup vs baseline: 4.4990x; 1.0750x over previous
//
#include <hip/hip_runtime.h>
#include <math.h>

#define NPTS 16384
#define KN 32
#define C 256
#define NQ 8192              // 8 * 1024 queries
#define PF_ELEMS (NQ * C)

#define W1P_ELEMS (3 * 16 * 64 * 8)                 // 24576  (Ktiles=3, Ntiles=16)
#define W2P_ELEMS (8 * 16 * 64 * 8)                 // 65536  (Ktiles=8)

typedef _Float16 half8 __attribute__((ext_vector_type(8)));
typedef _Float16 half4v __attribute__((ext_vector_type(4)));
typedef float f32x4 __attribute__((ext_vector_type(4)));

// ---------------------------------------------------------------------------
// Pack W1 (91x256, K-padded to 96) and W2 (256x256) into f16 B-fragment order
// for mfma_f32_16x16x32_f16 (layout verified in round 2):
//   flat = ((ktile*16 + ntile)*64 + lane)*8 + j
//   k = ktile*32 + (lane>>4)*8 + j ;  n = ntile*16 + (lane&15)
// ---------------------------------------------------------------------------
__global__ void prep_w_kernel(const float* __restrict__ W1,
                              const float* __restrict__ W2,
                              _Float16* __restrict__ wp) {
    const int e = blockIdx.x * 256 + threadIdx.x;
    if (e < W1P_ELEMS) {
        const int j = e & 7, lane = (e >> 3) & 63, nt = (e >> 9) & 15, kt = e >> 13;
        const int k = kt * 32 + (lane >> 4) * 8 + j;
        const int n = nt * 16 + (lane & 15);
        wp[e] = (_Float16)((k < 91) ? W1[k * C + n] : 0.0f);
    } else {
        const int e2 = e - W1P_ELEMS;
        const int j = e2 & 7, lane = (e2 >> 3) & 63, nt = (e2 >> 9) & 15, kt = e2 >> 13;
        const int k = kt * 32 + (lane >> 4) * 8 + j;
        const int n = nt * 16 + (lane & 15);
        wp[e] = (_Float16)W2[k * C + n];
    }
}

// tanh-approx GeLU: 0.5x(1+tanh(0.79788456(x+0.044715x^3))), max err ~3e-4.
// 1+tanh(u) = 2 - 2/(e^{2u}+1)  =>  y = x - x/(e^{2u}+1)
__device__ __forceinline__ float gelu_tanh(float x) {
    const float t  = x * x;
    const float p2 = fmaf(t, 0.0713548162726f, 1.59576912161f); // 2*0.79788456*(0.044715, 1)
    const float e  = __expf(x * p2);
    return x - x * __builtin_amdgcn_rcpf(e + 1.0f);
}

// ---------------------------------------------------------------------------
// Fused: ball-query + gather/posenc + MLP1(LN,GeLU) + MLP2(LN) + max.
// One query per 256-thread block (4 waves). f16 MFMA GEMMs, fp32 LN stats.
// Round-5 layout: in-place GEMM2 (single H16 buffer), LN threads own two
// 16-col chunks (bank spans (4row+8p)%32 -> 2-way = free), LDS ~28 KB ->
// 5 blocks/CU. All private-array indices compile-time (round-3 lesson).
// ---------------------------------------------------------------------------
__global__ void __launch_bounds__(256, 5)
encoder_fused(const float* __restrict__ xyz,
              const float* __restrict__ pf,
              const float* __restrict__ ctr,
              const float* __restrict__ b1, const float* __restrict__ g1,
              const float* __restrict__ be1,
              const float* __restrict__ b2, const float* __restrict__ g2,
              const float* __restrict__ be2,
              const _Float16* __restrict__ w1p,
              const _Float16* __restrict__ w2p,
              float* __restrict__ out0,      // patch_feature [8192][256]
              float* __restrict__ out1) {    // neighbor idx as float [8192][32]
    const int q = blockIdx.x;
    const int b = q >> 10;
    const int t = threadIdx.x;
    const int w = t >> 6;
    const int lane = t & 63;
    const int quad = lane >> 4;
    const int l15  = lane & 15;

    // H16: single f16 activation buffer, row stride 264 halves (528 B).
    // GEMM1 out -> LN1/GeLU in place -> GEMM2 A-src -> (barrier) GEMM2 out
    // in place -> LN2 in place -> max.
    __shared__ __align__(16) unsigned char H16raw[KN * 264 * 2];   // 16896
    __shared__ __align__(16) unsigned char Xsraw[KN * 104 * 2];    // 6656
    __shared__ float lnp[4 * 256];                                  // g1,be1,g2,be2
    __shared__ int nbr[KN];
    __shared__ int wcnt[4];

    _Float16 (*H16)[264] = (_Float16(*)[264])H16raw;
    _Float16 (*Xs)[104]  = (_Float16(*)[104])Xsraw;
    float* lng1  = lnp;        float* lnbe1 = lnp + 256;
    float* lng2  = lnp + 512;  float* lnbe2 = lnp + 768;

    // stage LN gamma/beta (visible after the ball-loop barriers)
    lnp[t]       = g1[t];  lnp[256 + t] = be1[t];
    lnp[512 + t] = g2[t];  lnp[768 + t] = be2[t];

    // ---- Phase 0: ball query, block-wide ordered compaction ----
    // Reference's sort+slice == first 32 indices (ascending) within radius.
    // Distance formula replicated exactly (fp32, unfused) as rounds 1-4.
    const float* xb = xyz + (size_t)b * NPTS * 3;
    const float cx = ctr[q * 3 + 0];
    const float cy = ctr[q * 3 + 1];
    const float cz = ctr[q * 3 + 2];
    const float sc = __fadd_rn(__fadd_rn(__fmul_rn(cx, cx), __fmul_rn(cy, cy)),
                               __fmul_rn(cz, cz));

    int found = 0;
    for (int base = 0; base < NPTS; base += 256) {
        const int n = base + t;
        const float px = xb[n * 3 + 0];
        const float py = xb[n * 3 + 1];
        const float pz = xb[n * 3 + 2];
        const float sp = __fadd_rn(__fadd_rn(__fmul_rn(px, px), __fmul_rn(py, py)),
                                   __fmul_rn(pz, pz));
        const float dt = __fadd_rn(__fadd_rn(__fmul_rn(cx, px), __fmul_rn(cy, py)),
                                   __fmul_rn(cz, pz));
        const float sqr = __fsub_rn(__fadd_rn(sc, sp), __fmul_rn(2.0f, dt));
        const bool inball = (sqr <= 0.0625f);

        const unsigned long long m = __ballot(inball);
        if (lane == 0) wcnt[w] = (int)__popcll(m);
        __syncthreads();
        int pre = found;
        if (w > 0) pre += wcnt[0];
        if (w > 1) pre += wcnt[1];
        if (w > 2) pre += wcnt[2];
        const int tot = found + wcnt[0] + wcnt[1] + wcnt[2] + wcnt[3];
        const int pos = pre + (int)__popcll(m & ((1ull << lane) - 1ull));
        if (inball && pos < KN) nbr[pos] = n;
        found = tot;
        __syncthreads();
        if (found >= KN) break;       // 'found' is block-uniform
    }
    const int count = (found < KN) ? found : KN;
    const int first = (count > 0) ? nbr[0] : NPTS;

    if (t < KN)
        out1[(size_t)q * KN + t] = (float)((t < count) ? nbr[t] : first);

    // ---- Phase 1: gather + rel + posenc into Xs (f16, K-padded to 96) ----
    {
        const int k  = t >> 3;          // neighbor row 0..31
        const int tc = t & 7;           // 8 threads per row
        const int nidx = (k < count) ? nbr[k] : first;
        const int n = (nidx < NPTS) ? nidx : NPTS - 1;   // JAX OOB gather clamp
        const float rx = xb[n * 3 + 0] - cx;
        const float ry = xb[n * 3 + 1] - cy;
        const float rz = xb[n * 3 + 2] - cz;
        const float* pfr = pf + ((size_t)b * NPTS + n) * 64;

        const float4 f0 = *(const float4*)(pfr + tc * 8);
        const float4 f1 = *(const float4*)(pfr + tc * 8 + 4);
        half8 hv;
        hv[0] = (_Float16)f0.x; hv[1] = (_Float16)f0.y;
        hv[2] = (_Float16)f0.z; hv[3] = (_Float16)f0.w;
        hv[4] = (_Float16)f1.x; hv[5] = (_Float16)f1.y;
        hv[6] = (_Float16)f1.z; hv[7] = (_Float16)f1.w;
        *(half8*)&Xs[k][tc * 8] = hv;

        half4v ov;
        #pragma unroll
        for (int j = 0; j < 4; ++j) {
            const int c = 64 + tc * 4 + j;
            float v;
            if (c < 67) {
                v = (c == 64) ? rx : ((c == 65) ? ry : rz);
            } else if (c < 91) {
                const int jj = c - 67;
                const int d = jj >> 3;
                const int mm = jj & 7;
                const float f = (float)(1 << (mm & 3));
                const float r = (d == 0) ? rx : ((d == 1) ? ry : rz);
                v = (mm < 4) ? __sinf(r * f) : __cosf(r * f);
            } else {
                v = 0.0f;
            }
            ov[j] = (_Float16)v;
        }
        *(half4v*)&Xs[k][64 + tc * 4] = ov;
    }
    __syncthreads();

    // ---- Phase 2: GEMM1  X[32x96] @ W1[96x256] -> H16 (+b1, f16) ----
    {
        f32x4 acc[2][4];
        #pragma unroll
        for (int mt = 0; mt < 2; ++mt)
            #pragma unroll
            for (int nt = 0; nt < 4; ++nt)
                acc[mt][nt] = (f32x4){0.f, 0.f, 0.f, 0.f};

        #pragma unroll
        for (int kt = 0; kt < 3; ++kt) {
            const half8 a0 = *(const half8*)&Xs[l15][kt * 32 + quad * 8];
            const half8 a1 = *(const half8*)&Xs[16 + l15][kt * 32 + quad * 8];
            #pragma unroll
            for (int nt = 0; nt < 4; ++nt) {
                const int ntg = w * 4 + nt;
                const half8 bf = *(const half8*)&w1p[((kt * 16 + ntg) * 64 + lane) * 8];
                acc[0][nt] = __builtin_amdgcn_mfma_f32_16x16x32_f16(a0, bf, acc[0][nt], 0, 0, 0);
                acc[1][nt] = __builtin_amdgcn_mfma_f32_16x16x32_f16(a1, bf, acc[1][nt], 0, 0, 0);
            }
        }
        #pragma unroll
        for (int nt = 0; nt < 4; ++nt) {
            const int col = w * 64 + nt * 16 + l15;
            const float bb = b1[col];          // global, L1-resident
            #pragma unroll
            for (int mt = 0; mt < 2; ++mt)
                #pragma unroll
                for (int r = 0; r < 4; ++r)
                    H16[mt * 16 + quad * 4 + r][col] = (_Float16)(acc[mt][nt][r] + bb);
        }
    }
    __syncthreads();

    const int row = t >> 3;         // LN ownership: thread = (row, octet p)
    const int p   = t & 7;          // owns cols [16p,16p+16) and [128+16p,+16)

    // ---- Phase 3: LN1 + GeLU, in place on H16 ----
    {
        _Float16* r0 = &H16[row][16 * p];
        _Float16* r1 = &H16[row][128 + 16 * p];
        const half8 h0 = *(const half8*)r0;
        const half8 h1 = *(const half8*)(r0 + 8);
        const half8 h2 = *(const half8*)r1;
        const half8 h3 = *(const half8*)(r1 + 8);

        float s = 0.0f, s2 = 0.0f;
        #pragma unroll
        for (int e = 0; e < 8; ++e) {
            const float x0 = (float)h0[e], x1 = (float)h1[e];
            const float x2 = (float)h2[e], x3 = (float)h3[e];
            s += (x0 + x1) + (x2 + x3);
            s2 = fmaf(x0, x0, fmaf(x1, x1, fmaf(x2, x2, fmaf(x3, x3, s2))));
        }
        #pragma unroll
        for (int off = 1; off < 8; off <<= 1) {
            s  += __shfl_xor(s, off, 64);
            s2 += __shfl_xor(s2, off, 64);
        }
        const float mu  = s * (1.0f / 256.0f);
        const float var = fmaf(s2, 1.0f / 256.0f, -mu * mu);
        const float rs  = __builtin_amdgcn_rsqf(var + 1e-5f);

        const int c0 = 16 * p, c1 = 128 + 16 * p;
        half8 o0, o1, o2, o3;
        #pragma unroll
        for (int e = 0; e < 8; ++e) {
            o0[e] = (_Float16)gelu_tanh(fmaf(((float)h0[e] - mu) * rs, lng1[c0 + e],     lnbe1[c0 + e]));
            o1[e] = (_Float16)gelu_tanh(fmaf(((float)h1[e] - mu) * rs, lng1[c0 + 8 + e], lnbe1[c0 + 8 + e]));
            o2[e] = (_Float16)gelu_tanh(fmaf(((float)h2[e] - mu) * rs, lng1[c1 + e],     lnbe1[c1 + e]));
            o3[e] = (_Float16)gelu_tanh(fmaf(((float)h3[e] - mu) * rs, lng1[c1 + 8 + e], lnbe1[c1 + 8 + e]));
        }
        *(half8*)r0       = o0;
        *(half8*)(r0 + 8) = o1;
        *(half8*)r1       = o2;
        *(half8*)(r1 + 8) = o3;
    }
    __syncthreads();

    // ---- Phase 4: GEMM2  H[32x256] @ W2[256x256] -> H16 in place (+b2) ----
    {
        f32x4 acc[2][4];
        #pragma unroll
        for (int mt = 0; mt < 2; ++mt)
            #pragma unroll
            for (int nt = 0; nt < 4; ++nt)
                acc[mt][nt] = (f32x4){0.f, 0.f, 0.f, 0.f};

        #pragma unroll
        for (int kt = 0; kt < 8; ++kt) {
            const half8 a0 = *(const half8*)&H16[l15][kt * 32 + quad * 8];
            const half8 a1 = *(const half8*)&H16[16 + l15][kt * 32 + quad * 8];
            #pragma unroll
            for (int nt = 0; nt < 4; ++nt) {
                const int ntg = w * 4 + nt;
                const half8 bf = *(const half8*)&w2p[((kt * 16 + ntg) * 64 + lane) * 8];
                acc[0][nt] = __builtin_amdgcn_mfma_f32_16x16x32_f16(a0, bf, acc[0][nt], 0, 0, 0);
                acc[1][nt] = __builtin_amdgcn_mfma_f32_16x16x32_f16(a1, bf, acc[1][nt], 0, 0, 0);
            }
        }
        __syncthreads();   // ALL A-reads of H16 complete before in-place store
        #pragma unroll
        for (int nt = 0; nt < 4; ++nt) {
            const int col = w * 64 + nt * 16 + l15;
            const float bb = b2[col];          // global, L1-resident
            #pragma unroll
            for (int mt = 0; mt < 2; ++mt)
                #pragma unroll
                for (int r = 0; r < 4; ++r)
                    H16[mt * 16 + quad * 4 + r][col] = (_Float16)(acc[mt][nt][r] + bb);
        }
    }
    __syncthreads();

    // ---- Phase 5: LN2 (no activation), in place on H16 ----
    {
        _Float16* r0 = &H16[row][16 * p];
        _Float16* r1 = &H16[row][128 + 16 * p];
        const half8 h0 = *(const half8*)r0;
        const half8 h1 = *(const half8*)(r0 + 8);
        const half8 h2 = *(const half8*)r1;
        const half8 h3 = *(const half8*)(r1 + 8);

        float s = 0.0f, s2 = 0.0f;
        #pragma unroll
        for (int e = 0; e < 8; ++e) {
            const float x0 = (float)h0[e], x1 = (float)h1[e];
            const float x2 = (float)h2[e], x3 = (float)h3[e];
            s += (x0 + x1) + (x2 + x3);
            s2 = fmaf(x0, x0, fmaf(x1, x1, fmaf(x2, x2, fmaf(x3, x3, s2))));
        }
        #pragma unroll
        for (int off = 1; off < 8; off <<= 1) {
            s  += __shfl_xor(s, off, 64);
            s2 += __shfl_xor(s2, off, 64);
        }
        const float mu  = s * (1.0f / 256.0f);
        const float var = fmaf(s2, 1.0f / 256.0f, -mu * mu);
        const float rs  = __builtin_amdgcn_rsqf(var + 1e-5f);

        const int c0 = 16 * p, c1 = 128 + 16 * p;
        half8 o0, o1, o2, o3;
        #pragma unroll
        for (int e = 0; e < 8; ++e) {
            o0[e] = (_Float16)fmaf(((float)h0[e] - mu) * rs, lng2[c0 + e],     lnbe2[c0 + e]);
            o1[e] = (_Float16)fmaf(((float)h1[e] - mu) * rs, lng2[c0 + 8 + e], lnbe2[c0 + 8 + e]);
            o2[e] = (_Float16)fmaf(((float)h2[e] - mu) * rs, lng2[c1 + e],     lnbe2[c1 + e]);
            o3[e] = (_Float16)fmaf(((float)h3[e] - mu) * rs, lng2[c1 + 8 + e], lnbe2[c1 + 8 + e]);
        }
        *(half8*)r0       = o0;
        *(half8*)(r0 + 8) = o1;
        *(half8*)r1       = o2;
        *(half8*)(r1 + 8) = o3;
    }
    __syncthreads();

    // ---- Phase 6: max over K per channel, write out ----
    {
        float m = -INFINITY;
        #pragma unroll
        for (int k = 0; k < KN; ++k)
            m = fmaxf(m, (float)H16[k][t]);
        out0[(size_t)q * C + t] = m;
    }
}

extern "C" void kernel_launch(void* const* d_in, const int* in_sizes, int n_in,
                              void* d_out, int out_size, void* d_ws, size_t ws_size,
                              hipStream_t stream) {
    const float* xyz = (const float*)d_in[0];
    const float* pf  = (const float*)d_in[1];
    const float* ctr = (const float*)d_in[2];
    const float* W1  = (const float*)d_in[3];
    const float* b1  = (const float*)d_in[4];
    const float* g1  = (const float*)d_in[5];
    const float* be1 = (const float*)d_in[6];
    const float* W2  = (const float*)d_in[7];
    const float* b2  = (const float*)d_in[8];
    const float* g2  = (const float*)d_in[9];
    const float* be2 = (const float*)d_in[10];

    float* out = (float*)d_out;
    _Float16* wp = (_Float16*)d_ws;

    prep_w_kernel<<<(W1P_ELEMS + W2P_ELEMS) / 256, 256, 0, stream>>>(W1, W2, wp);
    encoder_fused<<<NQ, 256, 0, stream>>>(xyz, pf, ctr,
                                          b1, g1, be1, b2, g2, be2,
                                          wp, wp + W1P_ELEMS,
                                          out, out + PF_ELEMS);
}